// Round 15
// baseline (1707.297 us; speedup 1.0000x reference)
//
#include <hip/hip_runtime.h>
#include <hip/hip_bf16.h>

#define N_NODES 4096
#define T_STEPS 8
#define INDIM   64
#define HDIM    128
#define G4      512                    // 4*H
#define NROWS   (N_NODES * T_STEPS)    // 32768
#define LOG2E   1.4426950408889634f

typedef __hip_bfloat16 bf16;
typedef __attribute__((ext_vector_type(8))) short bf16x8;
typedef __attribute__((ext_vector_type(4))) float f32x4;
typedef __attribute__((ext_vector_type(8))) int   i32x8;

__device__ __forceinline__ float asfloat_u(unsigned int u) {
    union { unsigned int i; float f; } v; v.i = u; return v.f;
}
// bare hardware exp2 (1 instr; OCML exp2f carries fixup code without fast-math)
__device__ __forceinline__ float fexp2(float x) {
    float r; asm("v_exp_f32 %0, %1" : "=v"(r) : "v"(x)); return r;
}

// ---------------- K0: fold weights + fp8 conversions + sync-var init ---------
#define P_O0 32768
#define P_O1 (P_O0 + 512)
#define P_O2 (P_O1 + 16384)
#define P_O3 (P_O2 + 16384)
#define P_O4 (P_O3 + 128)
#define P_O5 (P_O4 + 1)
#define P_O6 (P_O5 + 65536)
#define P_O7 (P_O6 + 128)
#define P_O8 (P_O7 + 4)
__global__ void prep_kernel(const float* __restrict__ pre_w, const float* __restrict__ pre_b,
                            const float* __restrict__ w_ih, const float* __restrict__ b_ih,
                            const float* __restrict__ b_hh, const float* __restrict__ w_hh,
                            const float* __restrict__ wsrc, const float* __restrict__ wdst,
                            const float* __restrict__ out_w, const float* __restrict__ out_b,
                            const float* __restrict__ gat_b, const float* __restrict__ attn,
                            float* __restrict__ Wc, float* __restrict__ bc,
                            float* __restrict__ wsT, float* __restrict__ wdT,
                            float* __restrict__ wso, float* __restrict__ cy,
                            unsigned char* __restrict__ whh8, float* __restrict__ attn2,
                            int* __restrict__ progress) {
    int id = blockIdx.x * 256 + threadIdx.x;
    if (id < P_O0) {
        int g = id >> 6, i = id & 63;
        float s = 0.f;
        for (int k = 0; k < HDIM; k++) s += pre_w[i * HDIM + k] * w_ih[g * HDIM + k];
        int gate = g >> 7;
        Wc[id] = s * ((gate == 2) ? -2.f * LOG2E : -LOG2E);
    } else if (id < P_O1) {
        int g = id - P_O0;
        float s = b_ih[g] + b_hh[g];
        for (int k = 0; k < HDIM; k++) s += pre_b[k] * w_ih[g * HDIM + k];
        int gate = g >> 7;
        bc[g] = s * ((gate == 2) ? -2.f * LOG2E : -LOG2E);
    } else if (id < P_O2) {
        int c = id - P_O1;
        int co = c >> 7, k = c & 127;
        wsT[c] = wsrc[k * HDIM + co];
    } else if (id < P_O3) {
        int c = id - P_O2;
        int co = c >> 7, k = c & 127;
        wdT[c] = wdst[k * HDIM + co];
    } else if (id < P_O4) {
        int hi = id - P_O3;
        float s = 0.f;
        for (int ho = 0; ho < HDIM; ho++) s += wsrc[hi * HDIM + ho] * out_w[ho];
        wso[hi] = s;
    } else if (id == P_O4) {
        float s = out_b[0];
        for (int h = 0; h < HDIM; h++) s += gat_b[h] * out_w[h];
        cy[0] = s;
    } else if (id < P_O6) {
        int c = id - P_O5;
        int gate = c >> 14;                      // row = c>>7, gate = row>>7
        float v = w_hh[c] * ((gate == 2) ? -2.f * LOG2E : -LOG2E);
        int pk = __builtin_amdgcn_cvt_pk_fp8_f32(v, v, 0, false);
        whh8[c] = (unsigned char)(pk & 0xff);
    } else if (id < P_O7) {
        int c = id - P_O6;
        attn2[c] = attn[c] * LOG2E;
    } else if (id < P_O8) {
        progress[id - P_O7] = 0;                 // re-init every call (graph replay)
    }
}

// ---------------- K1: xw[row][h*4+gate] = input[row,:64] . Wc[g,:] + bc[g] ---
__global__ __launch_bounds__(512) void xw_kernel(const float* __restrict__ input,
                                                 const float* __restrict__ Wc,
                                                 const float* __restrict__ bc,
                                                 bf16* __restrict__ xw) {
    __shared__ __align__(16) float in_lds[16 * INDIM];   // 4KB: 16 rows
    int tid = threadIdx.x;
    int rowbase = blockIdx.x * 16;
    in_lds[tid]       = input[(size_t)rowbase * INDIM + tid];
    in_lds[tid + 512] = input[(size_t)rowbase * INDIM + tid + 512];
    __syncthreads();
    int g = tid;
    int gate = g >> 7, hh = g & 127;
    float4 w[16];
    const float4* wr = reinterpret_cast<const float4*>(Wc + g * INDIM);
#pragma unroll
    for (int u = 0; u < 16; u++) w[u] = wr[u];
    float b = bc[g];
    for (int r = 0; r < 16; r++) {
        const float4* hv = reinterpret_cast<const float4*>(in_lds + r * INDIM);
        float a0 = b, a1 = 0.f, a2 = 0.f, a3 = 0.f;
#pragma unroll
        for (int u = 0; u < 16; u++) {
            float4 h4 = hv[u]; float4 wv = w[u];
            a0 = fmaf(h4.x, wv.x, a0); a1 = fmaf(h4.y, wv.y, a1);
            a2 = fmaf(h4.z, wv.z, a2); a3 = fmaf(h4.w, wv.w, a3);
        }
        xw[(size_t)(rowbase + r) * G4 + hh * 4 + gate] = __float2bfloat16((a0 + a1) + (a2 + a3));
    }
}

// ---------------- K2 fused: LSTM (0-3) + CSR (4) + fsfd (5..260) -------------
// LSTM blocks publish progress[b]=nodes-done every 256 nodes (vmcnt drain +
// block barrier + device release fence + agent atomic). fsfd blocks spin on
// min(progress[0..3]) then acquire-fence and process 128 rows each — hidden
// under the 1.37 ms scan. Residency-safe: 261 blocks <= 512 (worst-tier).
__global__ __launch_bounds__(256, 1) void lstm_kernel(const bf16* __restrict__ xw,
                                                      const unsigned char* __restrict__ whh8,
                                                      const float* __restrict__ hidden0,
                                                      const float* __restrict__ cell0,
                                                      float* __restrict__ outs,
                                                      float* __restrict__ dout,
                                                      const int* __restrict__ esrc,
                                                      const int* __restrict__ edst,
                                                      int nE,
                                                      int* __restrict__ rowptr,
                                                      int* __restrict__ ssrc,
                                                      const float* __restrict__ wsT,
                                                      const float* __restrict__ wdT,
                                                      const float* __restrict__ wso,
                                                      bf16* __restrict__ fs,
                                                      bf16* __restrict__ fd,
                                                      float* __restrict__ fso,
                                                      int* __restrict__ progress) {
    __shared__ __align__(16) char pool[17408];   // csr: cnt16K+part1K | fsfd: 16K | lstm: 576B
    const int tid = threadIdx.x;
    const int bid = blockIdx.x;

    if (bid == 4) {
        // ---- CSR build (256 threads) ----
        int* cnt  = (int*)pool;
        int* part = (int*)(pool + 16384);
        for (int i = tid; i < N_NODES; i += 256) cnt[i] = 0;
        __syncthreads();
        for (int i = tid; i < nE; i += 256) atomicAdd(&cnt[edst[i]], 1);
        __syncthreads();
        int base = tid * 16, loc[16], s = 0;
#pragma unroll
        for (int j = 0; j < 16; j++) { loc[j] = s; s += cnt[base + j]; }
        part[tid] = s;
        __syncthreads();
        for (int off = 1; off < 256; off <<= 1) {
            int v = (tid >= off) ? part[tid - off] : 0;
            __syncthreads();
            part[tid] += v;
            __syncthreads();
        }
        int pre = part[tid] - s;
#pragma unroll
        for (int j = 0; j < 16; j++) rowptr[base + j] = pre + loc[j];
        if (tid == 255) rowptr[N_NODES] = nE;
        __syncthreads();
#pragma unroll
        for (int j = 0; j < 16; j++) cnt[base + j] = pre + loc[j];
        __syncthreads();
        for (int i = tid; i < nE; i += 256) {
            int d = edst[i];
            int pos = atomicAdd(&cnt[d], 1);
            ssrc[pos] = esrc[i];
        }
        return;
    }

    if (bid >= 5) {
        // ---- fsfd: rows [fb*128, fb*128+128) of outs -> fs/fd/fso ----
        int fb = bid - 5;                        // 0..255
        int target = (fb + 1) * 16;              // nodes needed complete
        if (tid == 0) {
            for (;;) {
                int p0 = __hip_atomic_load(&progress[0], __ATOMIC_RELAXED, __HIP_MEMORY_SCOPE_AGENT);
                int p1 = __hip_atomic_load(&progress[1], __ATOMIC_RELAXED, __HIP_MEMORY_SCOPE_AGENT);
                int p2 = __hip_atomic_load(&progress[2], __ATOMIC_RELAXED, __HIP_MEMORY_SCOPE_AGENT);
                int p3 = __hip_atomic_load(&progress[3], __ATOMIC_RELAXED, __HIP_MEMORY_SCOPE_AGENT);
                int mn = min(min(p0, p1), min(p2, p3));
                if (mn >= target) break;
                __builtin_amdgcn_s_sleep(32);
            }
        }
        __syncthreads();
        __threadfence();                         // acquire: drop stale L2 lines
        float* rows = (float*)pool;              // 32 x 128 staging
        int c = tid;
        const float4* wT = reinterpret_cast<const float4*>(
            (c < HDIM) ? (wsT + c * HDIM) : (wdT + (c - HDIM) * HDIM));
        float4 w[32];
#pragma unroll
        for (int u = 0; u < 32; u++) w[u] = wT[u];
        for (int ch = 0; ch < 4; ch++) {
            int rowbase = fb * 128 + ch * 32;
            size_t base = (size_t)rowbase * HDIM;
            __syncthreads();                     // prior chunk reads done
#pragma unroll
            for (int j = 0; j < 16; j++) rows[tid + j * 256] = outs[base + tid + j * 256];
            __syncthreads();
            bf16* dst = (c < HDIM) ? (fs + base + c) : (fd + base + (c - HDIM));
            for (int r = 0; r < 32; r++) {
                const float4* hv = reinterpret_cast<const float4*>(rows + r * HDIM);
                float a0 = 0.f, a1 = 0.f, a2 = 0.f, a3 = 0.f;
#pragma unroll
                for (int u = 0; u < 32; u++) {
                    float4 h4 = hv[u]; float4 wv = w[u];
                    a0 = fmaf(h4.x, wv.x, a0); a1 = fmaf(h4.y, wv.y, a1);
                    a2 = fmaf(h4.z, wv.z, a2); a3 = fmaf(h4.w, wv.w, a3);
                }
                dst[(size_t)r * HDIM] = __float2bfloat16((a0 + a1) + (a2 + a3));
            }
            if (tid < 32) {
                const float* rp = rows + tid * HDIM;
                float s = 0.f;
                for (int k = 0; k < HDIM; k++) {
                    int kk = (k + tid) & 127;
                    s += rp[kk] * wso[kk];
                }
                fso[rowbase + tid] = s;
            }
        }
        return;
    }

    // ---- LSTM scan (blocks 0..3), 4 waves, 1 wave/SIMD ----
    char* hbuf0 = pool;
    char* hbuf1 = pool + 288;
    const int w    = tid >> 6;         // wave 0..3
    const int lane = tid & 63;
    const int kg   = lane >> 4;        // 0..3 (k-group of 32; C row block)
    const int lr   = lane & 15;        // A row in tile; C col
    const int q    = lr & 1;           // chain within block
    const int d    = (lr >> 1) & 3;    // which C reg this lane consumes
    const int b    = lr >> 3;          // which row-block tile
    const int qg   = bid * 2 + q;                     // global chain (t)
    const int hb   = 32 * w + 16 * b + kg * 4 + d;    // this lane's h index

    i32x8 afr[4][2];
#pragma unroll
    for (int G = 0; G < 4; G++)
#pragma unroll
        for (int bb = 0; bb < 2; bb++) {
            const unsigned char* rowp =
                whh8 + (size_t)(G * 128 + 32 * w + 16 * bb + lr) * HDIM + kg * 32;
            afr[G][bb] = *reinterpret_cast<const i32x8*>(rowp);
        }

    const int roff = q * 144 + kg * 32;
    const int woff = q * 144 + hb;
    const int sc   = 0x7f7f7f7f;

    float cv = cell0[qg * HDIM + hb];
    float hv = hidden0[qg * HDIM + hb];
    {
        int pk = __builtin_amdgcn_cvt_pk_fp8_f32(hv, hv, 0, false);
        *reinterpret_cast<unsigned char*>(hbuf0 + woff) = (unsigned char)(pk & 0xff);
    }

    const uint2* xq = reinterpret_cast<const uint2*>(xw) + qg * 128 + hb;
    float* outp = outs + qg * HDIM + hb;

    uint2 xb[8];
#pragma unroll
    for (int i = 0; i < 8; i++) xb[i] = xq[i * 1024];
    __syncthreads();

#define SEL(M) ((d & 2) ? ((d & 1) ? (M)[3] : (M)[2]) : ((d & 1) ? (M)[1] : (M)[0]))
#define STEPX(NIDX, RB, WB, XQ)                                                      \
    do {                                                                             \
        i32x8 bfr = *reinterpret_cast<const i32x8*>(RB + roff);                      \
        f32x4 z = {0.f, 0.f, 0.f, 0.f};                                              \
        f32x4 a00 = __builtin_amdgcn_mfma_scale_f32_16x16x128_f8f6f4(                \
            afr[0][0], bfr, z, 0, 0, 0, sc, 0, sc);                                  \
        f32x4 a01 = __builtin_amdgcn_mfma_scale_f32_16x16x128_f8f6f4(                \
            afr[0][1], bfr, z, 0, 0, 0, sc, 0, sc);                                  \
        f32x4 a10 = __builtin_amdgcn_mfma_scale_f32_16x16x128_f8f6f4(                \
            afr[1][0], bfr, z, 0, 0, 0, sc, 0, sc);                                  \
        f32x4 a11 = __builtin_amdgcn_mfma_scale_f32_16x16x128_f8f6f4(                \
            afr[1][1], bfr, z, 0, 0, 0, sc, 0, sc);                                  \
        f32x4 a20 = __builtin_amdgcn_mfma_scale_f32_16x16x128_f8f6f4(                \
            afr[2][0], bfr, z, 0, 0, 0, sc, 0, sc);                                  \
        f32x4 a21 = __builtin_amdgcn_mfma_scale_f32_16x16x128_f8f6f4(                \
            afr[2][1], bfr, z, 0, 0, 0, sc, 0, sc);                                  \
        f32x4 a30 = __builtin_amdgcn_mfma_scale_f32_16x16x128_f8f6f4(                \
            afr[3][0], bfr, z, 0, 0, 0, sc, 0, sc);                                  \
        f32x4 a31 = __builtin_amdgcn_mfma_scale_f32_16x16x128_f8f6f4(                \
            afr[3][1], bfr, z, 0, 0, 0, sc, 0, sc);                                  \
        f32x4 m0 = b ? a01 : a00;                                                    \
        f32x4 m1 = b ? a11 : a10;                                                    \
        f32x4 m2 = b ? a21 : a20;                                                    \
        f32x4 m3 = b ? a31 : a30;                                                    \
        float gi = SEL(m0) + asfloat_u((XQ).x << 16);                                \
        float gf = SEL(m1) + asfloat_u((XQ).x & 0xffff0000u);                        \
        float gg = SEL(m2) + asfloat_u((XQ).y << 16);                                \
        float go = SEL(m3) + asfloat_u((XQ).y & 0xffff0000u);                        \
        float A = fexp2(gi), C = fexp2(gf), B = fexp2(gg);                           \
        float p = 1.f + A, r = 1.f + B, s = 1.f + C;                                 \
        float pr = p * r;                                                            \
        float num = fmaf(cv, pr, (2.f - r) * s);                                     \
        cv = num * __builtin_amdgcn_rcpf(pr * s);                                    \
        float O = fexp2(go), F = fexp2(cv * (-2.f * LOG2E));                         \
        float po = 1.f + O, rf = 1.f + F;                                            \
        hv = (2.f - rf) * __builtin_amdgcn_rcpf(po * rf);                            \
        int pk = __builtin_amdgcn_cvt_pk_fp8_f32(hv, hv, 0, false);                  \
        *reinterpret_cast<unsigned char*>(WB + woff) = (unsigned char)(pk & 0xff);   \
        outp[(NIDX) * 1024] = hv;                                                    \
        asm volatile("s_waitcnt lgkmcnt(0)" ::: "memory");                           \
        __builtin_amdgcn_s_barrier();                                                \
        __builtin_amdgcn_sched_barrier(0);                                           \
    } while (0)

    for (int n = 0; n < N_NODES; n += 8) {
#pragma unroll
        for (int i = 0; i < 8; i++) {
            if (i & 1) STEPX(n + i, hbuf1, hbuf0, xb[i]);
            else       STEPX(n + i, hbuf0, hbuf1, xb[i]);
            // reload 8 steps ahead; tail reads land in outs region (in-bounds,
            // never consumed) so no conditionals needed
            xb[i] = xq[(n + i + 8) * 1024];
        }
        if ((n & 255) == 248) {
            // publish progress: drain outs stores, block-wide sync, release
            asm volatile("s_waitcnt vmcnt(0)" ::: "memory");
            __syncthreads();
            if (tid == 0) {
                __threadfence();                 // wbL2: make outs visible device-wide
                __hip_atomic_store(&progress[bid], n + 8, __ATOMIC_RELAXED,
                                   __HIP_MEMORY_SCOPE_AGENT);
            }
        }
    }
#undef STEPX
#undef SEL

    dout[NROWS + qg * HDIM + hb] = hv;                        // hT
    dout[NROWS + T_STEPS * HDIM + qg * HDIM + hb] = cv;       // cT
}

// ---------------- K4: per-dst edge softmax (CSR, no atomics) -----------------
__global__ __launch_bounds__(256) void edge_csr_kernel(const int* __restrict__ ssrc,
                                                       const int* __restrict__ rowptr,
                                                       const bf16* __restrict__ fs,
                                                       const bf16* __restrict__ fd,
                                                       const float* __restrict__ attn2,
                                                       const float* __restrict__ fso,
                                                       const float* __restrict__ cy,
                                                       float* __restrict__ dout) {
    int dn = blockIdx.x * 4 + (threadIdx.x >> 6);
    int l  = threadIdx.x & 63;
    float a0 = attn2[2 * l], a1 = attn2[2 * l + 1];
    const unsigned int* fdp = reinterpret_cast<const unsigned int*>(fd) + (size_t)dn * 512 + l;
    unsigned int fdw[8];
#pragma unroll
    for (int t = 0; t < 8; t++) fdw[t] = fdp[t * 64];
    float den[8], num[8];
#pragma unroll
    for (int t = 0; t < 8; t++) { den[t] = 0.f; num[t] = 0.f; }
    int e0 = rowptr[dn], e1 = rowptr[dn + 1];
    for (int e = e0; e < e1; e++) {
        int s = ssrc[e];
        const unsigned int* fsp = reinterpret_cast<const unsigned int*>(fs) + (size_t)s * 512 + l;
        float4 fsoA = *reinterpret_cast<const float4*>(fso + s * 8);
        float4 fsoB = *reinterpret_cast<const float4*>(fso + s * 8 + 4);
        float fsov[8] = {fsoA.x, fsoA.y, fsoA.z, fsoA.w, fsoB.x, fsoB.y, fsoB.z, fsoB.w};
#pragma unroll
        for (int t = 0; t < 8; t++) {
            unsigned int uf = fsp[t * 64];
            float x1 = asfloat_u(uf << 16) + asfloat_u(fdw[t] << 16);
            float x2 = asfloat_u(uf & 0xffff0000u) + asfloat_u(fdw[t] & 0xffff0000u);
            x1 = fmaxf(x1, 0.f) + 0.2f * fminf(x1, 0.f);
            x2 = fmaxf(x2, 0.f) + 0.2f * fminf(x2, 0.f);
            float v = x1 * a0 + x2 * a1;
#pragma unroll
            for (int m = 32; m >= 1; m >>= 1) v += __shfl_xor(v, m, 64);
            float a = fexp2(v);
            den[t] += a;
            num[t] = fmaf(a, fsov[t], num[t]);
        }
    }
    if (l == 0) {
        float cyv = cy[0];
        float4 y0, y1;
        y0.x = num[0] * __builtin_amdgcn_rcpf(den[0]) + cyv;
        y0.y = num[1] * __builtin_amdgcn_rcpf(den[1]) + cyv;
        y0.z = num[2] * __builtin_amdgcn_rcpf(den[2]) + cyv;
        y0.w = num[3] * __builtin_amdgcn_rcpf(den[3]) + cyv;
        y1.x = num[4] * __builtin_amdgcn_rcpf(den[4]) + cyv;
        y1.y = num[5] * __builtin_amdgcn_rcpf(den[5]) + cyv;
        y1.z = num[6] * __builtin_amdgcn_rcpf(den[6]) + cyv;
        y1.w = num[7] * __builtin_amdgcn_rcpf(den[7]) + cyv;
        *reinterpret_cast<float4*>(dout + dn * 8)     = y0;
        *reinterpret_cast<float4*>(dout + dn * 8 + 4) = y1;
    }
}

extern "C" void kernel_launch(void* const* d_in, const int* in_sizes, int n_in,
                              void* d_out, int out_size, void* d_ws, size_t ws_size,
                              hipStream_t stream) {
    const float* input  = (const float*)d_in[0];
    const float* hidden = (const float*)d_in[1];
    const float* cell   = (const float*)d_in[2];
    const float* pre_w  = (const float*)d_in[3];
    const float* pre_b  = (const float*)d_in[4];
    const float* w_ih   = (const float*)d_in[5];
    const float* w_hh   = (const float*)d_in[6];
    const float* b_ih   = (const float*)d_in[7];
    const float* b_hh   = (const float*)d_in[8];
    const float* wsrc   = (const float*)d_in[9];
    const float* wdst   = (const float*)d_in[10];
    const float* attn   = (const float*)d_in[11];
    const float* gatb   = (const float*)d_in[12];
    const float* outw   = (const float*)d_in[13];
    const float* outb   = (const float*)d_in[14];
    const int*   esrc   = (const int*)d_in[15];
    const int*   edst   = (const int*)d_in[16];
    int nE = in_sizes[15];
    float* dout = (float*)d_out;
    char* ws = (char*)d_ws;

    // workspace layout (bytes, 256-aligned)
    const size_t o_xw    = 0;                 // 32768*512*2  = 33,554,432
    const size_t o_outs  = 33554432;          // 32768*128*4  = 16,777,216
    const size_t o_fs    = 50331648;          //  8,388,608
    const size_t o_fd    = 58720256;          //  8,388,608
    const size_t o_fso   = 67108864;          //    131,072
    const size_t o_rowptr= 67272704;          //     16,640
    const size_t o_ssrc  = 67289344;          //    278,528 -> ends 67,567,872
                                              //    (overlaps Wc/bc: dead after xw;
                                              //     written by lstm-dispatch block 4)
    const size_t o_wc    = 67502080;          //    131,072  (dead after xw_kernel)
    const size_t o_bc    = 67633152;          //      2,048
    const size_t o_wsT   = 67635200;          //     65,536
    const size_t o_wdT   = 67700736;          //     65,536
    const size_t o_wso   = 67766272;          //        512
    const size_t o_cy    = 67766784;          //        256 (4 used)
    const size_t o_attn2 = 67767040;          //        512
    const size_t o_prog  = 67767552;          //         16 (progress[4])
    const size_t o_whh8  = o_fs;              // fp8 w_hh overlaps fs (disjoint in time)

    bf16*  xw    = (bf16*)(ws + o_xw);
    float* outs  = (float*)(ws + o_outs);
    bf16*  fs    = (bf16*)(ws + o_fs);
    bf16*  fd    = (bf16*)(ws + o_fd);
    float* fso   = (float*)(ws + o_fso);
    int*   rowptr= (int*)(ws + o_rowptr);
    int*   ssrc  = (int*)(ws + o_ssrc);
    float* Wc    = (float*)(ws + o_wc);
    float* bc    = (float*)(ws + o_bc);
    float* wsT   = (float*)(ws + o_wsT);
    float* wdT   = (float*)(ws + o_wdT);
    float* wso   = (float*)(ws + o_wso);
    float* cy    = (float*)(ws + o_cy);
    float* attn2 = (float*)(ws + o_attn2);
    int*   prog  = (int*)(ws + o_prog);
    unsigned char* whh8 = (unsigned char*)(ws + o_whh8);

    prep_kernel<<<516, 256, 0, stream>>>(pre_w, pre_b, w_ih, b_ih, b_hh, w_hh, wsrc, wdst,
                                         outw, outb, gatb, attn,
                                         Wc, bc, wsT, wdT, wso, cy, whh8, attn2, prog);
    xw_kernel<<<2048, 512, 0, stream>>>(input, Wc, bc, xw);
    lstm_kernel<<<261, 256, 0, stream>>>(xw, whh8, hidden, cell, outs, dout,
                                         esrc, edst, nE, rowptr, ssrc,
                                         wsT, wdT, wso, fs, fd, fso, prog);
    edge_csr_kernel<<<N_NODES / 4, 256, 0, stream>>>(ssrc, rowptr, fs, fd, attn2, fso, cy, dout);
}

// Round 16
// 1651.573 us; speedup vs baseline: 1.0337x; 1.0337x over previous
//
#include <hip/hip_runtime.h>
#include <hip/hip_bf16.h>

#define N_NODES 4096
#define T_STEPS 8
#define INDIM   64
#define HDIM    128
#define G4      512                    // 4*H
#define NROWS   (N_NODES * T_STEPS)    // 32768
#define LOG2E   1.4426950408889634f

typedef __hip_bfloat16 bf16;
typedef __attribute__((ext_vector_type(8))) short bf16x8;
typedef __attribute__((ext_vector_type(4))) float f32x4;
typedef __attribute__((ext_vector_type(8))) int   i32x8;

__device__ __forceinline__ float asfloat_u(unsigned int u) {
    union { unsigned int i; float f; } v; v.i = u; return v.f;
}
// bare hardware exp2 (1 instr; OCML exp2f carries fixup code without fast-math)
__device__ __forceinline__ float fexp2(float x) {
    float r; asm("v_exp_f32 %0, %1" : "=v"(r) : "v"(x)); return r;
}

// ---------------- K0: fold weights + fp8 conversions -------------------------
// Gate pre-scaling: gates i,f,o rows scaled by -log2e, gate g rows by -2*log2e
// (device exp chains are bare v_exp_f32 = 2^x). attn2 = attn*log2e (edge exp).
#define P_O0 32768
#define P_O1 (P_O0 + 512)
#define P_O2 (P_O1 + 16384)
#define P_O3 (P_O2 + 16384)
#define P_O4 (P_O3 + 128)
#define P_O5 (P_O4 + 1)
#define P_O6 (P_O5 + 65536)
#define P_O7 (P_O6 + 128)
__global__ void prep_kernel(const float* __restrict__ pre_w, const float* __restrict__ pre_b,
                            const float* __restrict__ w_ih, const float* __restrict__ b_ih,
                            const float* __restrict__ b_hh, const float* __restrict__ w_hh,
                            const float* __restrict__ wsrc, const float* __restrict__ wdst,
                            const float* __restrict__ out_w, const float* __restrict__ out_b,
                            const float* __restrict__ gat_b, const float* __restrict__ attn,
                            float* __restrict__ Wc, float* __restrict__ bc,
                            float* __restrict__ wsT, float* __restrict__ wdT,
                            float* __restrict__ wso, float* __restrict__ cy,
                            unsigned char* __restrict__ whh8, float* __restrict__ attn2) {
    int id = blockIdx.x * 256 + threadIdx.x;
    if (id < P_O0) {
        int g = id >> 6, i = id & 63;
        float s = 0.f;
        for (int k = 0; k < HDIM; k++) s += pre_w[i * HDIM + k] * w_ih[g * HDIM + k];
        int gate = g >> 7;
        Wc[id] = s * ((gate == 2) ? -2.f * LOG2E : -LOG2E);
    } else if (id < P_O1) {
        int g = id - P_O0;
        float s = b_ih[g] + b_hh[g];
        for (int k = 0; k < HDIM; k++) s += pre_b[k] * w_ih[g * HDIM + k];
        int gate = g >> 7;
        bc[g] = s * ((gate == 2) ? -2.f * LOG2E : -LOG2E);
    } else if (id < P_O2) {
        int c = id - P_O1;
        int co = c >> 7, k = c & 127;
        wsT[c] = wsrc[k * HDIM + co];
    } else if (id < P_O3) {
        int c = id - P_O2;
        int co = c >> 7, k = c & 127;
        wdT[c] = wdst[k * HDIM + co];
    } else if (id < P_O4) {
        int hi = id - P_O3;
        float s = 0.f;
        for (int ho = 0; ho < HDIM; ho++) s += wsrc[hi * HDIM + ho] * out_w[ho];
        wso[hi] = s;
    } else if (id == P_O4) {
        float s = out_b[0];
        for (int h = 0; h < HDIM; h++) s += gat_b[h] * out_w[h];
        cy[0] = s;
    } else if (id < P_O6) {
        int c = id - P_O5;
        int gate = c >> 14;                      // row = c>>7, gate = row>>7
        float v = w_hh[c] * ((gate == 2) ? -2.f * LOG2E : -LOG2E);
        int pk = __builtin_amdgcn_cvt_pk_fp8_f32(v, v, 0, false);
        whh8[c] = (unsigned char)(pk & 0xff);
    } else if (id < P_O7) {
        int c = id - P_O6;
        attn2[c] = attn[c] * LOG2E;
    }
}

// ---------------- K1: xw[row][h*4+gate] = input[row,:64] . Wc[g,:] + bc[g] ---
__global__ __launch_bounds__(512) void xw_kernel(const float* __restrict__ input,
                                                 const float* __restrict__ Wc,
                                                 const float* __restrict__ bc,
                                                 bf16* __restrict__ xw) {
    __shared__ __align__(16) float in_lds[16 * INDIM];   // 4KB: 16 rows
    int tid = threadIdx.x;
    int rowbase = blockIdx.x * 16;
    in_lds[tid]       = input[(size_t)rowbase * INDIM + tid];
    in_lds[tid + 512] = input[(size_t)rowbase * INDIM + tid + 512];
    __syncthreads();
    int g = tid;
    int gate = g >> 7, hh = g & 127;
    float4 w[16];
    const float4* wr = reinterpret_cast<const float4*>(Wc + g * INDIM);
#pragma unroll
    for (int u = 0; u < 16; u++) w[u] = wr[u];
    float b = bc[g];
    for (int r = 0; r < 16; r++) {
        const float4* hv = reinterpret_cast<const float4*>(in_lds + r * INDIM);
        float a0 = b, a1 = 0.f, a2 = 0.f, a3 = 0.f;
#pragma unroll
        for (int u = 0; u < 16; u++) {
            float4 h4 = hv[u]; float4 wv = w[u];
            a0 = fmaf(h4.x, wv.x, a0); a1 = fmaf(h4.y, wv.y, a1);
            a2 = fmaf(h4.z, wv.z, a2); a3 = fmaf(h4.w, wv.w, a3);
        }
        xw[(size_t)(rowbase + r) * G4 + hh * 4 + gate] = __float2bfloat16((a0 + a1) + (a2 + a3));
    }
}

// ---------------- K2: LSTM scan (blocks 0-3) + CSR build (block 4) -----------
// LSTM: 4 blocks x 2 chains, 256 threads (4 waves) => 1 wave/SIMD, no issue
// contention. Wave w covers h rows [32w,32w+32) via 8 A-tiles (G x rowblock b).
// Lane (kg,lr): q=lr&1 (chain), d=(lr>>1)&3 (C reg), b=lr>>3 (tile half)
// -> unique (h,chain) per lane, 1 h of gate math each (zero duplication).
// Block 4: dst-sorted CSR build (LDS hist/scan/scatter), hidden under the scan.
__global__ __launch_bounds__(256, 1) void lstm_kernel(const bf16* __restrict__ xw,
                                                      const unsigned char* __restrict__ whh8,
                                                      const float* __restrict__ hidden0,
                                                      const float* __restrict__ cell0,
                                                      float* __restrict__ outs,
                                                      float* __restrict__ dout,
                                                      const int* __restrict__ esrc,
                                                      const int* __restrict__ edst,
                                                      int nE,
                                                      int* __restrict__ rowptr,
                                                      int* __restrict__ ssrc) {
    __shared__ __align__(16) char hbuf0[2 * 144];
    __shared__ __align__(16) char hbuf1[2 * 144];
    __shared__ int cnt[N_NODES];       // 16KB (csr block only)
    __shared__ int part[256];
    const int tid  = threadIdx.x;

    if (blockIdx.x == 4) {
        // ---- CSR build (256 threads) ----
        for (int i = tid; i < N_NODES; i += 256) cnt[i] = 0;
        __syncthreads();
        for (int i = tid; i < nE; i += 256) atomicAdd(&cnt[edst[i]], 1);
        __syncthreads();
        int base = tid * 16, loc[16], s = 0;
#pragma unroll
        for (int j = 0; j < 16; j++) { loc[j] = s; s += cnt[base + j]; }
        part[tid] = s;
        __syncthreads();
        for (int off = 1; off < 256; off <<= 1) {
            int v = (tid >= off) ? part[tid - off] : 0;
            __syncthreads();
            part[tid] += v;
            __syncthreads();
        }
        int pre = part[tid] - s;
#pragma unroll
        for (int j = 0; j < 16; j++) rowptr[base + j] = pre + loc[j];
        if (tid == 255) rowptr[N_NODES] = nE;
        __syncthreads();
#pragma unroll
        for (int j = 0; j < 16; j++) cnt[base + j] = pre + loc[j];
        __syncthreads();
        for (int i = tid; i < nE; i += 256) {
            int d = edst[i];
            int pos = atomicAdd(&cnt[d], 1);
            ssrc[pos] = esrc[i];
        }
        return;
    }

    // ---- LSTM scan ----
    const int w    = tid >> 6;         // wave 0..3
    const int lane = tid & 63;
    const int kg   = lane >> 4;        // 0..3 (k-group of 32; C row block)
    const int lr   = lane & 15;        // A row in tile; C col
    const int q    = lr & 1;           // chain within block
    const int d    = (lr >> 1) & 3;    // which C reg this lane consumes
    const int b    = lr >> 3;          // which row-block tile
    const int qg   = blockIdx.x * 2 + q;              // global chain (t)
    const int hb   = 32 * w + 16 * b + kg * 4 + d;    // this lane's h index

    // Persistent A fragments: tile (G, bb) rows G*128 + 32w + 16bb + lr
    i32x8 afr[4][2];
#pragma unroll
    for (int G = 0; G < 4; G++)
#pragma unroll
        for (int bb = 0; bb < 2; bb++) {
            const unsigned char* rowp =
                whh8 + (size_t)(G * 128 + 32 * w + 16 * bb + lr) * HDIM + kg * 32;
            afr[G][bb] = *reinterpret_cast<const i32x8*>(rowp);
        }

    const int roff = q * 144 + kg * 32;   // B-frag read base (32 contiguous bytes)
    const int woff = q * 144 + hb;        // h write (1 byte)
    const int sc   = 0x7f7f7f7f;          // e8m0 scale 1.0 in every byte

    float cv = cell0[qg * HDIM + hb];
    float hv = hidden0[qg * HDIM + hb];
    {
        int pk = __builtin_amdgcn_cvt_pk_fp8_f32(hv, hv, 0, false);
        *reinterpret_cast<unsigned char*>(hbuf0 + woff) = (unsigned char)(pk & 0xff);
    }

    // xw: row (n*8+qg), this h's 4 gates = 8 bytes -> uint2 idx row*128 + hb
    const uint2* xq = reinterpret_cast<const uint2*>(xw) + qg * 128 + hb;
    float* outp = outs + qg * HDIM + hb;

    uint2 xb[8];
#pragma unroll
    for (int i = 0; i < 8; i++) xb[i] = xq[i * 1024];
    __syncthreads();

#define SEL(M) ((d & 2) ? ((d & 1) ? (M)[3] : (M)[2]) : ((d & 1) ? (M)[1] : (M)[0]))
#define STEPX(NIDX, RB, WB, XQ)                                                      \
    do {                                                                             \
        i32x8 bfr = *reinterpret_cast<const i32x8*>(RB + roff);                      \
        f32x4 z = {0.f, 0.f, 0.f, 0.f};                                              \
        f32x4 a00 = __builtin_amdgcn_mfma_scale_f32_16x16x128_f8f6f4(                \
            afr[0][0], bfr, z, 0, 0, 0, sc, 0, sc);                                  \
        f32x4 a01 = __builtin_amdgcn_mfma_scale_f32_16x16x128_f8f6f4(                \
            afr[0][1], bfr, z, 0, 0, 0, sc, 0, sc);                                  \
        f32x4 a10 = __builtin_amdgcn_mfma_scale_f32_16x16x128_f8f6f4(                \
            afr[1][0], bfr, z, 0, 0, 0, sc, 0, sc);                                  \
        f32x4 a11 = __builtin_amdgcn_mfma_scale_f32_16x16x128_f8f6f4(                \
            afr[1][1], bfr, z, 0, 0, 0, sc, 0, sc);                                  \
        f32x4 a20 = __builtin_amdgcn_mfma_scale_f32_16x16x128_f8f6f4(                \
            afr[2][0], bfr, z, 0, 0, 0, sc, 0, sc);                                  \
        f32x4 a21 = __builtin_amdgcn_mfma_scale_f32_16x16x128_f8f6f4(                \
            afr[2][1], bfr, z, 0, 0, 0, sc, 0, sc);                                  \
        f32x4 a30 = __builtin_amdgcn_mfma_scale_f32_16x16x128_f8f6f4(                \
            afr[3][0], bfr, z, 0, 0, 0, sc, 0, sc);                                  \
        f32x4 a31 = __builtin_amdgcn_mfma_scale_f32_16x16x128_f8f6f4(                \
            afr[3][1], bfr, z, 0, 0, 0, sc, 0, sc);                                  \
        f32x4 m0 = b ? a01 : a00;                                                    \
        f32x4 m1 = b ? a11 : a10;                                                    \
        f32x4 m2 = b ? a21 : a20;                                                    \
        f32x4 m3 = b ? a31 : a30;                                                    \
        float gi = SEL(m0) + asfloat_u((XQ).x << 16);                                \
        float gf = SEL(m1) + asfloat_u((XQ).x & 0xffff0000u);                        \
        float gg = SEL(m2) + asfloat_u((XQ).y << 16);                                \
        float go = SEL(m3) + asfloat_u((XQ).y & 0xffff0000u);                        \
        float A = fexp2(gi), C = fexp2(gf), B = fexp2(gg);                           \
        float p = 1.f + A, r = 1.f + B, s = 1.f + C;                                 \
        float pr = p * r;                                                            \
        float num = fmaf(cv, pr, (2.f - r) * s);                                     \
        cv = num * __builtin_amdgcn_rcpf(pr * s);                                    \
        float O = fexp2(go), F = fexp2(cv * (-2.f * LOG2E));                         \
        float po = 1.f + O, rf = 1.f + F;                                            \
        hv = (2.f - rf) * __builtin_amdgcn_rcpf(po * rf);                            \
        int pk = __builtin_amdgcn_cvt_pk_fp8_f32(hv, hv, 0, false);                  \
        *reinterpret_cast<unsigned char*>(WB + woff) = (unsigned char)(pk & 0xff);   \
        outp[(NIDX) * 1024] = hv;                                                    \
        asm volatile("s_waitcnt lgkmcnt(0)" ::: "memory");                           \
        __builtin_amdgcn_s_barrier();                                                \
        __builtin_amdgcn_sched_barrier(0);                                           \
    } while (0)

    for (int n = 0; n < N_NODES; n += 8) {
#pragma unroll
        for (int i = 0; i < 8; i++) {
            if (i & 1) STEPX(n + i, hbuf1, hbuf0, xb[i]);
            else       STEPX(n + i, hbuf0, hbuf1, xb[i]);
            // reload 8 steps ahead; tail reads land in outs region (in-bounds,
            // never consumed) so no conditionals needed
            xb[i] = xq[(n + i + 8) * 1024];
        }
    }
#undef STEPX
#undef SEL

    dout[NROWS + qg * HDIM + hb] = hv;                        // hT
    dout[NROWS + T_STEPS * HDIM + qg * HDIM + hb] = cv;       // cT
}

// ---------------- K3: fs/fd GEMV + fused fso ---------------------------------
__global__ __launch_bounds__(256) void fsfd_kernel(const float* __restrict__ outs,
                                                   const float* __restrict__ wsT,
                                                   const float* __restrict__ wdT,
                                                   const float* __restrict__ wso,
                                                   bf16* __restrict__ fs,
                                                   bf16* __restrict__ fd,
                                                   float* __restrict__ fso) {
    __shared__ __align__(16) float rows[32 * HDIM];    // 16KB: 32 rows
    int tid = threadIdx.x;
    size_t base = (size_t)blockIdx.x * 32 * HDIM;
#pragma unroll
    for (int j = 0; j < 16; j++) rows[tid + j * 256] = outs[base + tid + j * 256];
    __syncthreads();
    int c = tid;
    const float4* wT = reinterpret_cast<const float4*>(
        (c < HDIM) ? (wsT + c * HDIM) : (wdT + (c - HDIM) * HDIM));
    float4 w[32];
#pragma unroll
    for (int u = 0; u < 32; u++) w[u] = wT[u];
    bf16* dst = (c < HDIM) ? (fs + base + c) : (fd + base + (c - HDIM));
    for (int r = 0; r < 32; r++) {
        const float4* hv = reinterpret_cast<const float4*>(rows + r * HDIM);
        float a0 = 0.f, a1 = 0.f, a2 = 0.f, a3 = 0.f;
#pragma unroll
        for (int u = 0; u < 32; u++) {
            float4 h4 = hv[u]; float4 wv = w[u];
            a0 = fmaf(h4.x, wv.x, a0); a1 = fmaf(h4.y, wv.y, a1);
            a2 = fmaf(h4.z, wv.z, a2); a3 = fmaf(h4.w, wv.w, a3);
        }
        dst[(size_t)r * HDIM] = __float2bfloat16((a0 + a1) + (a2 + a3));
    }
    // fused fso: row-dot with wso (rotation k' = (k+tid)&127 -> conflict-free)
    if (tid < 32) {
        const float* rp = rows + tid * HDIM;
        float s = 0.f;
        for (int k = 0; k < HDIM; k++) {
            int kk = (k + tid) & 127;
            s += rp[kk] * wso[kk];
        }
        fso[blockIdx.x * 32 + tid] = s;
    }
}

// ---------------- K4: per-dst edge softmax (CSR, no atomics) -----------------
// 4 dst per block (4 waves). Lane l covers h-pair (2l, 2l+1). fd row dwords in
// registers; per source edge: vectorized fs dword loads, leaky+dot, butterfly
// reduce, a=2^v, accumulate den/num in regs. Lane 0 writes y = num/den + cy.
__global__ __launch_bounds__(256) void edge_csr_kernel(const int* __restrict__ ssrc,
                                                       const int* __restrict__ rowptr,
                                                       const bf16* __restrict__ fs,
                                                       const bf16* __restrict__ fd,
                                                       const float* __restrict__ attn2,
                                                       const float* __restrict__ fso,
                                                       const float* __restrict__ cy,
                                                       float* __restrict__ dout) {
    int dn = blockIdx.x * 4 + (threadIdx.x >> 6);
    int l  = threadIdx.x & 63;
    float a0 = attn2[2 * l], a1 = attn2[2 * l + 1];
    const unsigned int* fdp = reinterpret_cast<const unsigned int*>(fd) + (size_t)dn * 512 + l;
    unsigned int fdw[8];
#pragma unroll
    for (int t = 0; t < 8; t++) fdw[t] = fdp[t * 64];
    float den[8], num[8];
#pragma unroll
    for (int t = 0; t < 8; t++) { den[t] = 0.f; num[t] = 0.f; }
    int e0 = rowptr[dn], e1 = rowptr[dn + 1];
    for (int e = e0; e < e1; e++) {
        int s = ssrc[e];
        const unsigned int* fsp = reinterpret_cast<const unsigned int*>(fs) + (size_t)s * 512 + l;
        float4 fsoA = *reinterpret_cast<const float4*>(fso + s * 8);
        float4 fsoB = *reinterpret_cast<const float4*>(fso + s * 8 + 4);
        float fsov[8] = {fsoA.x, fsoA.y, fsoA.z, fsoA.w, fsoB.x, fsoB.y, fsoB.z, fsoB.w};
#pragma unroll
        for (int t = 0; t < 8; t++) {
            unsigned int uf = fsp[t * 64];
            float x1 = asfloat_u(uf << 16) + asfloat_u(fdw[t] << 16);
            float x2 = asfloat_u(uf & 0xffff0000u) + asfloat_u(fdw[t] & 0xffff0000u);
            x1 = fmaxf(x1, 0.f) + 0.2f * fminf(x1, 0.f);
            x2 = fmaxf(x2, 0.f) + 0.2f * fminf(x2, 0.f);
            float v = x1 * a0 + x2 * a1;
#pragma unroll
            for (int m = 32; m >= 1; m >>= 1) v += __shfl_xor(v, m, 64);
            float a = fexp2(v);
            den[t] += a;
            num[t] = fmaf(a, fsov[t], num[t]);
        }
    }
    if (l == 0) {
        float cyv = cy[0];
        float4 y0, y1;
        y0.x = num[0] * __builtin_amdgcn_rcpf(den[0]) + cyv;
        y0.y = num[1] * __builtin_amdgcn_rcpf(den[1]) + cyv;
        y0.z = num[2] * __builtin_amdgcn_rcpf(den[2]) + cyv;
        y0.w = num[3] * __builtin_amdgcn_rcpf(den[3]) + cyv;
        y1.x = num[4] * __builtin_amdgcn_rcpf(den[4]) + cyv;
        y1.y = num[5] * __builtin_amdgcn_rcpf(den[5]) + cyv;
        y1.z = num[6] * __builtin_amdgcn_rcpf(den[6]) + cyv;
        y1.w = num[7] * __builtin_amdgcn_rcpf(den[7]) + cyv;
        *reinterpret_cast<float4*>(dout + dn * 8)     = y0;
        *reinterpret_cast<float4*>(dout + dn * 8 + 4) = y1;
    }
}

extern "C" void kernel_launch(void* const* d_in, const int* in_sizes, int n_in,
                              void* d_out, int out_size, void* d_ws, size_t ws_size,
                              hipStream_t stream) {
    const float* input  = (const float*)d_in[0];
    const float* hidden = (const float*)d_in[1];
    const float* cell   = (const float*)d_in[2];
    const float* pre_w  = (const float*)d_in[3];
    const float* pre_b  = (const float*)d_in[4];
    const float* w_ih   = (const float*)d_in[5];
    const float* w_hh   = (const float*)d_in[6];
    const float* b_ih   = (const float*)d_in[7];
    const float* b_hh   = (const float*)d_in[8];
    const float* wsrc   = (const float*)d_in[9];
    const float* wdst   = (const float*)d_in[10];
    const float* attn   = (const float*)d_in[11];
    const float* gatb   = (const float*)d_in[12];
    const float* outw   = (const float*)d_in[13];
    const float* outb   = (const float*)d_in[14];
    const int*   esrc   = (const int*)d_in[15];
    const int*   edst   = (const int*)d_in[16];
    int nE = in_sizes[15];
    float* dout = (float*)d_out;
    char* ws = (char*)d_ws;

    // workspace layout (bytes, 256-aligned)
    const size_t o_xw    = 0;                 // 32768*512*2  = 33,554,432
    const size_t o_outs  = 33554432;          // 32768*128*4  = 16,777,216
    const size_t o_fs    = 50331648;          //  8,388,608
    const size_t o_fd    = 58720256;          //  8,388,608
    const size_t o_fso   = 67108864;          //    131,072
    const size_t o_rowptr= 67272704;          //     16,640
    const size_t o_ssrc  = 67289344;          //    278,528 -> ends 67,567,872
                                              //    (overlaps Wc/bc: dead after xw;
                                              //     written by lstm-dispatch block 4)
    const size_t o_wc    = 67502080;          //    131,072  (dead after xw_kernel)
    const size_t o_bc    = 67633152;          //      2,048
    const size_t o_wsT   = 67635200;          //     65,536
    const size_t o_wdT   = 67700736;          //     65,536
    const size_t o_wso   = 67766272;          //        512
    const size_t o_cy    = 67766784;          //        256 (4 used)
    const size_t o_attn2 = 67767040;          //        512
    const size_t o_whh8  = o_fs;              // fp8 w_hh overlaps fs (disjoint in time)

    bf16*  xw    = (bf16*)(ws + o_xw);
    float* outs  = (float*)(ws + o_outs);
    bf16*  fs    = (bf16*)(ws + o_fs);
    bf16*  fd    = (bf16*)(ws + o_fd);
    float* fso   = (float*)(ws + o_fso);
    int*   rowptr= (int*)(ws + o_rowptr);
    int*   ssrc  = (int*)(ws + o_ssrc);
    float* Wc    = (float*)(ws + o_wc);
    float* bc    = (float*)(ws + o_bc);
    float* wsT   = (float*)(ws + o_wsT);
    float* wdT   = (float*)(ws + o_wdT);
    float* wso   = (float*)(ws + o_wso);
    float* cy    = (float*)(ws + o_cy);
    float* attn2 = (float*)(ws + o_attn2);
    unsigned char* whh8 = (unsigned char*)(ws + o_whh8);

    prep_kernel<<<516, 256, 0, stream>>>(pre_w, pre_b, w_ih, b_ih, b_hh, w_hh, wsrc, wdst,
                                         outw, outb, gatb, attn,
                                         Wc, bc, wsT, wdT, wso, cy, whh8, attn2);
    xw_kernel<<<2048, 512, 0, stream>>>(input, Wc, bc, xw);
    lstm_kernel<<<5, 256, 0, stream>>>(xw, whh8, hidden, cell, outs, dout,
                                       esrc, edst, nE, rowptr, ssrc);
    fsfd_kernel<<<1024, 256, 0, stream>>>(outs, wsT, wdT, wso, fs, fd, fso);
    edge_csr_kernel<<<N_NODES / 4, 256, 0, stream>>>(ssrc, rowptr, fs, fd, attn2, fso, cy, dout);
}